// Round 4
// baseline (706.327 us; speedup 1.0000x reference)
//
#include <hip/hip_runtime.h>
#include <hip/hip_bf16.h>
#include <stdint.h>

typedef _Float16 half8 __attribute__((ext_vector_type(8)));
typedef float f32x4 __attribute__((ext_vector_type(4)));
typedef float f32x16 __attribute__((ext_vector_type(16)));

#define T_STEPS 20
#define B_SZ 512
#define D_IN 4096
#define H_SZ 1024
#define C_SZ 100
#define M_TOT (T_STEPS * B_SZ)  // 10240
#define BK 32
#define KITERS (D_IN / BK)  // 128

// ---------- helpers ----------
__device__ __forceinline__ void gload16(const _Float16* g, _Float16* l) {
  __builtin_amdgcn_global_load_lds(
      (const __attribute__((address_space(1))) void*)g,
      (__attribute__((address_space(3))) void*)l, 16, 0, 0);
}

// 8 fp32 -> half8 hi + half8 lo residual
struct HL {
  half8 h;
  half8 l;
};
__device__ __forceinline__ HL split8(float4 a, float4 b) {
  HL r;
  auto p0 = __builtin_amdgcn_cvt_pkrtz(a.x, a.y);
  auto p1 = __builtin_amdgcn_cvt_pkrtz(a.z, a.w);
  auto p2 = __builtin_amdgcn_cvt_pkrtz(b.x, b.y);
  auto p3 = __builtin_amdgcn_cvt_pkrtz(b.z, b.w);
  r.h[0] = p0.x; r.h[1] = p0.y; r.h[2] = p1.x; r.h[3] = p1.y;
  r.h[4] = p2.x; r.h[5] = p2.y; r.h[6] = p3.x; r.h[7] = p3.y;
  auto q0 = __builtin_amdgcn_cvt_pkrtz(a.x - (float)p0.x, a.y - (float)p0.y);
  auto q1 = __builtin_amdgcn_cvt_pkrtz(a.z - (float)p1.x, a.w - (float)p1.y);
  auto q2 = __builtin_amdgcn_cvt_pkrtz(b.x - (float)p2.x, b.y - (float)p2.y);
  auto q3 = __builtin_amdgcn_cvt_pkrtz(b.z - (float)p3.x, b.w - (float)p3.y);
  r.l[0] = q0.x; r.l[1] = q0.y; r.l[2] = q1.x; r.l[3] = q1.y;
  r.l[4] = q2.x; r.l[5] = q2.y; r.l[6] = q3.x; r.l[7] = q3.y;
  return r;
}

// ---------- prep: fp32 row-major -> fp16 hi/lo planes in 32x32 FRAGMENT-TILE order
// (unchanged — both global sides coalesced via swizzled LDS transpose)
__global__ __launch_bounds__(256) void k_prep_frag(
    const float* __restrict__ Z, _Float16* __restrict__ Azh,
    _Float16* __restrict__ Azl, const float* __restrict__ W1,
    _Float16* __restrict__ Wfh, _Float16* __restrict__ Wfl) {
  __shared__ float sL[32 * 256];  // 32 KB

  const int cc = blockIdx.x;      // 256-col chunk (8 ki values)
  int rt = blockIdx.y >> 2;       // 128-row tile
  const int rb = blockIdx.y & 3;  // 32-row block within tile
  const float* src;
  _Float16 *dh, *dl;
  if (rt < 80) {
    src = Z; dh = Azh; dl = Azl;
  } else {
    rt -= 80; src = W1; dh = Wfh; dl = Wfl;
  }
  const int tid = threadIdx.x;
  const int lane64 = tid & 63;
  const int w4 = tid >> 6;  // 0..3

  // ---- read phase: 8 iters x (4 rows x 256 cols) ----
  const int row_base = rt * 128 + rb * 32;
  float4 v[8];
#pragma unroll
  for (int it = 0; it < 8; ++it) {
    const int row_local = it * 4 + w4;
    v[it] = *(const float4*)(src + (int64_t)(row_base + row_local) * D_IN +
                             cc * 256 + lane64 * 4);
  }
#pragma unroll
  for (int it = 0; it < 8; ++it) {
    const int row_local = it * 4 + w4;
    const int c = (lane64 * 4) ^ ((row_local & 7) << 2);
    *(float4*)&sL[row_local * 256 + c] = v[it];
  }
  __syncthreads();

  // ---- write phase: 4 iters, one octet per thread per iter ----
  const int s = (tid >> 6) & 1;
  const int hi = (tid >> 5) & 1;
  const int l31 = tid & 31;
  const int q = s * 2 + hi;
  const int sw = (l31 & 7) << 2;
#pragma unroll
  for (int it2 = 0; it2 < 4; ++it2) {
    const int kil = it2 * 2 + (tid >> 7);  // 0..7
    const int c0 = kil * 32 + q * 8;
    float4 a = *(const float4*)&sL[l31 * 256 + (c0 ^ sw)];
    float4 b = *(const float4*)&sL[l31 * 256 + ((c0 + 4) ^ sw)];
    HL hl = split8(a, b);
    const int64_t d = ((int64_t)(rt * 128 + cc * 8 + kil)) * 4096 +
                      (rb * 128 + s * 64 + hi * 32 + l31) * 8;
    *(half8*)&dh[d] = hl.h;
    *(half8*)&dl[d] = hl.l;
  }
}

// W2 [100][1024] -> padded [112][1024] hi/lo (pad rows zero)
__global__ void k_prep_w2(const float* __restrict__ w2, _Float16* __restrict__ hi,
                          _Float16* __restrict__ lo) {
  int i = blockIdx.x * 256 + threadIdx.x;
  float v = (i < C_SZ * H_SZ) ? w2[i] : 0.0f;
  _Float16 h = (_Float16)v;
  hi[i] = h;
  lo[i] = (_Float16)(v - (float)h);
}

// ---------- big GEMM: Hbuf = Z * W1^T, 3-term fp16 split ----------
// 2-phase double-buffered LDS (T3 minimum recipe). Round-2 counters: 278.6 us
// = 925 TF eff = m97 1-phase ceiling; barrier drained vmcnt(0) with zero
// overlap (MfmaUtil 43%). Next-tile glds issued BEFORE current tile's
// ds_read+MFMA; the __syncthreads vmcnt(0) drain IS the next-tile wait.
// Race-free: barrier at end of iter k-1 guarantees buf^1 readers done before
// iter k stages into it. 64 KB LDS -> 2 blocks/CU, static buf idx via 2x unroll.
__global__ __launch_bounds__(256) void k_gemm1(
    const _Float16* __restrict__ Ahi, const _Float16* __restrict__ Alo,
    const _Float16* __restrict__ Whi, const _Float16* __restrict__ Wlo,
    float* __restrict__ Hbuf) {
  __shared__ _Float16 sAh[2][4096];
  __shared__ _Float16 sAl[2][4096];
  __shared__ _Float16 sWh[2][4096];
  __shared__ _Float16 sWl[2][4096];

  const int tid = threadIdx.x;
  const int lane = tid & 63;
  const int w = tid >> 6;

  const int bid = blockIdx.x;          // 0..639, XCD-band swizzle
  const int xcd = bid & 7;
  const int qb = bid >> 3;
  const int mt = xcd * 10 + (qb >> 3);
  const int nt = qb & 7;

  // staging: wave w stages frag-blocks w and w+4; src contiguous 1 KiB/issue
  const int ls = w * 512 + lane * 8;   // LDS f16 idx (wave-uniform + lane*16B)
  const _Float16* gAh = Ahi + (int64_t)mt * (128 * 4096) + ls;
  const _Float16* gAl = Alo + (int64_t)mt * (128 * 4096) + ls;
  const _Float16* gWh = Whi + (int64_t)nt * (128 * 4096) + ls;
  const _Float16* gWl = Wlo + (int64_t)nt * (128 * 4096) + ls;

  // frag read bases (conflict-free: lane*16B linear)
  const int wm = (w >> 1) * 64;
  const int wn = (w & 1) * 64;
  const int ra = (wm >> 4) * 512 + lane * 8;
  const int rbb = (wn >> 4) * 512 + lane * 8;

  f32x16 acc[2][2] = {};

  auto stage = [&](int buf, int ki) {
    const int64_t so = (int64_t)ki * 4096;
    gload16(gAh + so, &sAh[buf][ls]);
    gload16(gAh + so + 2048, &sAh[buf][ls + 2048]);
    gload16(gAl + so, &sAl[buf][ls]);
    gload16(gAl + so + 2048, &sAl[buf][ls + 2048]);
    gload16(gWh + so, &sWh[buf][ls]);
    gload16(gWh + so + 2048, &sWh[buf][ls + 2048]);
    gload16(gWl + so, &sWl[buf][ls]);
    gload16(gWl + so + 2048, &sWl[buf][ls + 2048]);
  };

  auto compute = [&](int buf) {
    half8 ah[2][2], al[2][2], bh[2][2], bl[2][2];
#pragma unroll
    for (int i = 0; i < 2; ++i) {
#pragma unroll
      for (int s = 0; s < 2; ++s) {
        ah[i][s] = *(const half8*)&sAh[buf][ra + (i * 2 + s) * 512];
        al[i][s] = *(const half8*)&sAl[buf][ra + (i * 2 + s) * 512];
        bh[i][s] = *(const half8*)&sWh[buf][rbb + (i * 2 + s) * 512];
        bl[i][s] = *(const half8*)&sWl[buf][rbb + (i * 2 + s) * 512];
      }
    }
#pragma unroll
    for (int a = 0; a < 2; ++a) {
#pragma unroll
      for (int b = 0; b < 2; ++b) {
#pragma unroll
        for (int s = 0; s < 2; ++s) {
          acc[a][b] = __builtin_amdgcn_mfma_f32_32x32x16_f16(ah[a][s], bh[b][s], acc[a][b], 0, 0, 0);
          acc[a][b] = __builtin_amdgcn_mfma_f32_32x32x16_f16(ah[a][s], bl[b][s], acc[a][b], 0, 0, 0);
          acc[a][b] = __builtin_amdgcn_mfma_f32_32x32x16_f16(al[a][s], bh[b][s], acc[a][b], 0, 0, 0);
        }
      }
    }
  };

  // prologue: tile 0 into buf 0
  stage(0, 0);
  __syncthreads();  // vmcnt(0) drain: tile 0 ready

  // steady state, 2x-unrolled for static buffer indices.
  // even tiles live in buf 0, odd tiles in buf 1.
  for (int ki = 0; ki < KITERS; ki += 2) {
    if (ki + 1 < KITERS) stage(1, ki + 1);  // issue next-tile loads FIRST
    compute(0);                             // overlap: ds_read+MFMA over glds
    __syncthreads();                        // drain = next-tile ready
    if (ki + 2 < KITERS) stage(0, ki + 2);
    compute(1);
    __syncthreads();
  }

  // epilogue: C/D 32x32 layout col=lane&31, row=(reg&3)+8*(reg>>2)+4*(lane>>5)
  const int64_t m0 = (int64_t)mt * 128;
  const int n0 = nt * 128;
  const int l31 = lane & 31;
  const int h2 = lane >> 5;
#pragma unroll
  for (int a = 0; a < 2; ++a) {
#pragma unroll
    for (int b = 0; b < 2; ++b) {
      float* dst = Hbuf + (m0 + wm + a * 32 + h2 * 4) * H_SZ + n0 + wn + b * 32 + l31;
#pragma unroll
      for (int r4 = 0; r4 < 4; ++r4) {
#pragma unroll
        for (int r = 0; r < 4; ++r) {
          dst[(int64_t)(r4 * 8 + r) * H_SZ] = acc[a][b][r4 * 4 + r];
        }
      }
    }
  }
}

// ---------- BN stats: 64-wide coalesced column sums ----------
__global__ void k_stats(const float* __restrict__ Hbuf, const float* __restrict__ gamma,
                        float* __restrict__ scale, float* __restrict__ shift) {
  const int t = blockIdx.y;
  const int tx = threadIdx.x & 63;
  const int ty = threadIdx.x >> 6;  // 0..3
  const int h = blockIdx.x * 64 + tx;
  const float* p = Hbuf + ((int64_t)t * B_SZ + ty * 128) * H_SZ + h;
  float s = 0.f, s2 = 0.f;
#pragma unroll 8
  for (int i = 0; i < 128; ++i) {
    float v = p[(int64_t)i * H_SZ];
    s += v;
    s2 += v * v;
  }
  __shared__ float ss[4][64];
  __shared__ float sq[4][64];
  ss[ty][tx] = s;
  sq[ty][tx] = s2;
  __syncthreads();
  if (ty == 0) {
    float a = ss[0][tx] + ss[1][tx] + ss[2][tx] + ss[3][tx];
    float b = sq[0][tx] + sq[1][tx] + sq[2][tx] + sq[3][tx];
    const float mean = a * (1.0f / B_SZ);
    const float var = b * (1.0f / B_SZ) - mean * mean;
    const float rs = rsqrtf(var + 1e-4f);
    const float sc = gamma[t * H_SZ + h] * rs;
    scale[t * H_SZ + h] = sc;
    shift[t * H_SZ + h] = -mean * sc;
  }
}

// ---------- LIF recurrence per (b,h): spike count S ----------
__global__ void k_recur(const float* __restrict__ Hbuf, const float* __restrict__ scale,
                        const float* __restrict__ shift, _Float16* __restrict__ S) {
  const int idx = blockIdx.x * 256 + threadIdx.x;
  const int b = idx >> 10;
  const int h = idx & 1023;
  float mem = 0.f;
  int cnt = 0;
#pragma unroll
  for (int t = 0; t < T_STEPS; ++t) {
    float v = Hbuf[((int64_t)(t * B_SZ + b) << 10) + h];
    v = v * scale[(t << 10) + h] + shift[(t << 10) + h];
    mem = 0.95f * mem + v;
    if (mem - 1.0f > 0.0f) {
      ++cnt;
      mem -= 1.0f;
    }
  }
  S[idx] = (_Float16)cnt;
}

// ---------- GEMM2: out = S @ W2^T / 20, 2-term fp16 split (exact: S integer) ----------
__global__ void k_gemm2(const _Float16* __restrict__ S, const _Float16* __restrict__ W2h,
                        const _Float16* __restrict__ W2l, float* __restrict__ out) {
  const int wid = threadIdx.x >> 6;
  const int lane = threadIdx.x & 63;
  const int m0 = blockIdx.y * 64 + wid * 16;
  const int n0 = blockIdx.x * 16;
  const int fr = lane & 15;
  const int quad = lane >> 4;

  const _Float16* sp = S + (int64_t)(m0 + fr) * H_SZ + quad * 8;
  const _Float16* wph = W2h + (int64_t)(n0 + fr) * H_SZ + quad * 8;
  const _Float16* wpl = W2l + (int64_t)(n0 + fr) * H_SZ + quad * 8;

  f32x4 acc = {0.f, 0.f, 0.f, 0.f};
#pragma unroll 4
  for (int k = 0; k < H_SZ; k += 32) {
    half8 a = *(const half8*)(sp + k);
    half8 bh = *(const half8*)(wph + k);
    half8 bl = *(const half8*)(wpl + k);
    acc = __builtin_amdgcn_mfma_f32_16x16x32_f16(a, bh, acc, 0, 0, 0);
    acc = __builtin_amdgcn_mfma_f32_16x16x32_f16(a, bl, acc, 0, 0, 0);
  }
  const int col = n0 + fr;
  if (col < C_SZ) {
#pragma unroll
    for (int r = 0; r < 4; ++r) {
      const int row = m0 + quad * 4 + r;
      out[row * C_SZ + col] = acc[r] * (1.0f / T_STEPS);
    }
  }
}

extern "C" void kernel_launch(void* const* d_in, const int* in_sizes, int n_in,
                              void* d_out, int out_size, void* d_ws, size_t ws_size,
                              hipStream_t stream) {
  const float* z = (const float*)d_in[0];      // [20,512,4096]
  const float* W1 = (const float*)d_in[1];     // [1024,4096]
  const float* gamma = (const float*)d_in[2];  // [20,1024]
  const float* W2 = (const float*)d_in[3];     // [100,1024]
  float* out = (float*)d_out;                  // [512,100]

  char* ws = (char*)d_ws;
  size_t off = 0;
  auto alloc = [&](size_t bytes) -> void* {
    void* p = ws + off;
    off += (bytes + 255) & ~(size_t)255;
    return p;
  };
  _Float16* Azh = (_Float16*)alloc((size_t)M_TOT * D_IN * 2);
  _Float16* Azl = (_Float16*)alloc((size_t)M_TOT * D_IN * 2);
  _Float16* Wfh = (_Float16*)alloc((size_t)H_SZ * D_IN * 2);
  _Float16* Wfl = (_Float16*)alloc((size_t)H_SZ * D_IN * 2);
  float* Hbuf = (float*)alloc((size_t)M_TOT * H_SZ * 4);
  float* scale = (float*)alloc((size_t)T_STEPS * H_SZ * 4);
  float* shift = (float*)alloc((size_t)T_STEPS * H_SZ * 4);
  _Float16* S = (_Float16*)alloc((size_t)B_SZ * H_SZ * 2);
  _Float16* W2h = (_Float16*)alloc((size_t)112 * H_SZ * 2);
  _Float16* W2l = (_Float16*)alloc((size_t)112 * H_SZ * 2);

  // 1) z + W1 -> fragment-tiled fp16 hi/lo planes (LDS-transposed, coalesced); W2 hi/lo
  dim3 gp(16, 352);  // 16 col-chunks x (88 rt * 4 rb)
  k_prep_frag<<<gp, 256, 0, stream>>>(z, Azh, Azl, W1, Wfh, Wfl);
  k_prep_w2<<<(112 * H_SZ) / 256, 256, 0, stream>>>(W2, W2h, W2l);

  // 2) batched fc1 GEMM (32x32x16 MFMA, 2-phase double-buffered LDS)
  k_gemm1<<<640, 256, 0, stream>>>(Azh, Azl, Wfh, Wfl, Hbuf);

  // 3) BN stats
  dim3 gs(H_SZ / 64, T_STEPS);  // (16, 20)
  k_stats<<<gs, 256, 0, stream>>>(Hbuf, gamma, scale, shift);

  // 4) LIF recurrence -> spike counts
  k_recur<<<(B_SZ * H_SZ) / 256, 256, 0, stream>>>(Hbuf, scale, shift, S);

  // 5) spike-count GEMM -> output
  dim3 g2(7, 8);
  k_gemm2<<<g2, 256, 0, stream>>>(S, W2h, W2l, out);
}

// Round 5
// 541.939 us; speedup vs baseline: 1.3033x; 1.3033x over previous
//
#include <hip/hip_runtime.h>
#include <hip/hip_bf16.h>
#include <stdint.h>

typedef _Float16 half8 __attribute__((ext_vector_type(8)));
typedef float f32x4 __attribute__((ext_vector_type(4)));
typedef float f32x16 __attribute__((ext_vector_type(16)));

#define T_STEPS 20
#define B_SZ 512
#define D_IN 4096
#define H_SZ 1024
#define C_SZ 100
#define M_TOT (T_STEPS * B_SZ)  // 10240
#define BK 32
#define KITERS (D_IN / BK)   // 128
#define KHALF (KITERS / 2)   // 64 per split-K block
#define HPLANE ((int64_t)M_TOT * H_SZ)  // elements per partial plane

// ---------- helpers ----------
__device__ __forceinline__ void gload16(const _Float16* g, _Float16* l) {
  __builtin_amdgcn_global_load_lds(
      (const __attribute__((address_space(1))) void*)g,
      (__attribute__((address_space(3))) void*)l, 16, 0, 0);
}

// 8 fp32 -> half8 hi + half8 lo residual
struct HL {
  half8 h;
  half8 l;
};
__device__ __forceinline__ HL split8(float4 a, float4 b) {
  HL r;
  auto p0 = __builtin_amdgcn_cvt_pkrtz(a.x, a.y);
  auto p1 = __builtin_amdgcn_cvt_pkrtz(a.z, a.w);
  auto p2 = __builtin_amdgcn_cvt_pkrtz(b.x, b.y);
  auto p3 = __builtin_amdgcn_cvt_pkrtz(b.z, b.w);
  r.h[0] = p0.x; r.h[1] = p0.y; r.h[2] = p1.x; r.h[3] = p1.y;
  r.h[4] = p2.x; r.h[5] = p2.y; r.h[6] = p3.x; r.h[7] = p3.y;
  auto q0 = __builtin_amdgcn_cvt_pkrtz(a.x - (float)p0.x, a.y - (float)p0.y);
  auto q1 = __builtin_amdgcn_cvt_pkrtz(a.z - (float)p1.x, a.w - (float)p1.y);
  auto q2 = __builtin_amdgcn_cvt_pkrtz(b.x - (float)p2.x, b.y - (float)p2.y);
  auto q3 = __builtin_amdgcn_cvt_pkrtz(b.z - (float)p3.x, b.w - (float)p3.y);
  r.l[0] = q0.x; r.l[1] = q0.y; r.l[2] = q1.x; r.l[3] = q1.y;
  r.l[4] = q2.x; r.l[5] = q2.y; r.l[6] = q3.x; r.l[7] = q3.y;
  return r;
}

// ---------- prep: fp32 row-major -> fp16 hi/lo planes in 32x32 FRAGMENT-TILE order
// (unchanged — both global sides coalesced via swizzled LDS transpose)
__global__ __launch_bounds__(256) void k_prep_frag(
    const float* __restrict__ Z, _Float16* __restrict__ Azh,
    _Float16* __restrict__ Azl, const float* __restrict__ W1,
    _Float16* __restrict__ Wfh, _Float16* __restrict__ Wfl) {
  __shared__ float sL[32 * 256];  // 32 KB

  const int cc = blockIdx.x;      // 256-col chunk (8 ki values)
  int rt = blockIdx.y >> 2;       // 128-row tile
  const int rb = blockIdx.y & 3;  // 32-row block within tile
  const float* src;
  _Float16 *dh, *dl;
  if (rt < 80) {
    src = Z; dh = Azh; dl = Azl;
  } else {
    rt -= 80; src = W1; dh = Wfh; dl = Wfl;
  }
  const int tid = threadIdx.x;
  const int lane64 = tid & 63;
  const int w4 = tid >> 6;  // 0..3

  // ---- read phase: 8 iters x (4 rows x 256 cols) ----
  const int row_base = rt * 128 + rb * 32;
  float4 v[8];
#pragma unroll
  for (int it = 0; it < 8; ++it) {
    const int row_local = it * 4 + w4;
    v[it] = *(const float4*)(src + (int64_t)(row_base + row_local) * D_IN +
                             cc * 256 + lane64 * 4);
  }
#pragma unroll
  for (int it = 0; it < 8; ++it) {
    const int row_local = it * 4 + w4;
    const int c = (lane64 * 4) ^ ((row_local & 7) << 2);
    *(float4*)&sL[row_local * 256 + c] = v[it];
  }
  __syncthreads();

  // ---- write phase: 4 iters, one octet per thread per iter ----
  const int s = (tid >> 6) & 1;
  const int hi = (tid >> 5) & 1;
  const int l31 = tid & 31;
  const int q = s * 2 + hi;
  const int sw = (l31 & 7) << 2;
#pragma unroll
  for (int it2 = 0; it2 < 4; ++it2) {
    const int kil = it2 * 2 + (tid >> 7);  // 0..7
    const int c0 = kil * 32 + q * 8;
    float4 a = *(const float4*)&sL[l31 * 256 + (c0 ^ sw)];
    float4 b = *(const float4*)&sL[l31 * 256 + ((c0 + 4) ^ sw)];
    HL hl = split8(a, b);
    const int64_t d = ((int64_t)(rt * 128 + cc * 8 + kil)) * 4096 +
                      (rb * 128 + s * 64 + hi * 32 + l31) * 8;
    *(half8*)&dh[d] = hl.h;
    *(half8*)&dl[d] = hl.l;
  }
}

// W2 [100][1024] -> padded [112][1024] hi/lo (pad rows zero)
__global__ void k_prep_w2(const float* __restrict__ w2, _Float16* __restrict__ hi,
                          _Float16* __restrict__ lo) {
  int i = blockIdx.x * 256 + threadIdx.x;
  float v = (i < C_SZ * H_SZ) ? w2[i] : 0.0f;
  _Float16 h = (_Float16)v;
  hi[i] = h;
  lo[i] = (_Float16)(v - (float)h);
}

// ---------- big GEMM: Hpart[kh] = Z * W1^T (K-half kh), 3-term fp16 split ----------
// REVERT to the verified 1-phase single-buffer 32 KB structure (R2: 278.6 us).
// Round-4 post-mortem: 64 KB dbuf cut residency to ~1 block/CU (occupancy 13%,
// MfmaUtil 25%, 432 us) — cross-block overlap was the real pipeline (m132 trap).
// CHANGE: split-K x2. Grid 640 -> 1280 blocks, each does 64 K-iters into its
// own 40 MB partial plane; k_stats/k_recur fold the sum. Avg 5 blocks/CU
// scheduled (uniform), ~3 resident by regs -> barrier drains hidden by
// co-resident blocks' MFMA.
__global__ __launch_bounds__(256) void k_gemm1(
    const _Float16* __restrict__ Ahi, const _Float16* __restrict__ Alo,
    const _Float16* __restrict__ Whi, const _Float16* __restrict__ Wlo,
    float* __restrict__ Hpart) {
  __shared__ _Float16 sAh[4096];
  __shared__ _Float16 sAl[4096];
  __shared__ _Float16 sWh[4096];
  __shared__ _Float16 sWl[4096];

  const int tid = threadIdx.x;
  const int lane = tid & 63;
  const int w = tid >> 6;

  // bid in [0,1280): xcd-band swizzle; within XCD: mt band of 10, all nt, both kh
  const int bid = blockIdx.x;
  const int xcd = bid & 7;
  const int q = bid >> 3;        // 0..159
  const int mtl = q >> 4;        // 0..9
  const int r = q & 15;
  const int nt = r >> 1;         // 0..7
  const int kh = r & 1;          // K-half
  const int mt = xcd * 10 + mtl;

  // staging: wave w stages frag-blocks w and w+4; src contiguous 1 KiB/issue
  const int ls = w * 512 + lane * 8;   // LDS f16 idx (wave-uniform + lane*16B)
  const _Float16* gAh = Ahi + (int64_t)mt * (128 * 4096) + ls;
  const _Float16* gAl = Alo + (int64_t)mt * (128 * 4096) + ls;
  const _Float16* gWh = Whi + (int64_t)nt * (128 * 4096) + ls;
  const _Float16* gWl = Wlo + (int64_t)nt * (128 * 4096) + ls;

  // frag read bases (conflict-free: lane*16B linear)
  const int wm = (w >> 1) * 64;
  const int wn = (w & 1) * 64;
  const int ra = (wm >> 4) * 512 + lane * 8;
  const int rbb = (wn >> 4) * 512 + lane * 8;

  f32x16 acc[2][2] = {};

  const int k0 = kh * KHALF;
  for (int ki = k0; ki < k0 + KHALF; ++ki) {
    const int64_t so = (int64_t)ki * 4096;
    __syncthreads();
    gload16(gAh + so, &sAh[ls]);
    gload16(gAh + so + 2048, &sAh[ls + 2048]);
    gload16(gAl + so, &sAl[ls]);
    gload16(gAl + so + 2048, &sAl[ls + 2048]);
    gload16(gWh + so, &sWh[ls]);
    gload16(gWh + so + 2048, &sWh[ls + 2048]);
    gload16(gWl + so, &sWl[ls]);
    gload16(gWl + so + 2048, &sWl[ls + 2048]);
    __syncthreads();

    half8 ah[2][2], al[2][2], bh[2][2], bl[2][2];
#pragma unroll
    for (int i = 0; i < 2; ++i) {
#pragma unroll
      for (int s = 0; s < 2; ++s) {
        ah[i][s] = *(const half8*)&sAh[ra + (i * 2 + s) * 512];
        al[i][s] = *(const half8*)&sAl[ra + (i * 2 + s) * 512];
        bh[i][s] = *(const half8*)&sWh[rbb + (i * 2 + s) * 512];
        bl[i][s] = *(const half8*)&sWl[rbb + (i * 2 + s) * 512];
      }
    }
#pragma unroll
    for (int a = 0; a < 2; ++a) {
#pragma unroll
      for (int b = 0; b < 2; ++b) {
#pragma unroll
        for (int s = 0; s < 2; ++s) {
          acc[a][b] = __builtin_amdgcn_mfma_f32_32x32x16_f16(ah[a][s], bh[b][s], acc[a][b], 0, 0, 0);
          acc[a][b] = __builtin_amdgcn_mfma_f32_32x32x16_f16(ah[a][s], bl[b][s], acc[a][b], 0, 0, 0);
          acc[a][b] = __builtin_amdgcn_mfma_f32_32x32x16_f16(al[a][s], bh[b][s], acc[a][b], 0, 0, 0);
        }
      }
    }
  }

  // epilogue: C/D 32x32 layout col=lane&31, row=(reg&3)+8*(reg>>2)+4*(lane>>5)
  float* Hb = Hpart + (int64_t)kh * HPLANE;
  const int64_t m0 = (int64_t)mt * 128;
  const int n0 = nt * 128;
  const int l31 = lane & 31;
  const int h2 = lane >> 5;
#pragma unroll
  for (int a = 0; a < 2; ++a) {
#pragma unroll
    for (int b = 0; b < 2; ++b) {
      float* dst = Hb + (m0 + wm + a * 32 + h2 * 4) * H_SZ + n0 + wn + b * 32 + l31;
#pragma unroll
      for (int r4 = 0; r4 < 4; ++r4) {
#pragma unroll
        for (int rr = 0; rr < 4; ++rr) {
          dst[(int64_t)(r4 * 8 + rr) * H_SZ] = acc[a][b][r4 * 4 + rr];
        }
      }
    }
  }
}

// ---------- BN stats: 64-wide coalesced column sums over (plane0 + plane1) ----------
__global__ void k_stats(const float* __restrict__ Hpart, const float* __restrict__ gamma,
                        float* __restrict__ scale, float* __restrict__ shift) {
  const int t = blockIdx.y;
  const int tx = threadIdx.x & 63;
  const int ty = threadIdx.x >> 6;  // 0..3
  const int h = blockIdx.x * 64 + tx;
  const float* p0 = Hpart + ((int64_t)t * B_SZ + ty * 128) * H_SZ + h;
  const float* p1 = p0 + HPLANE;
  float s = 0.f, s2 = 0.f;
#pragma unroll 8
  for (int i = 0; i < 128; ++i) {
    float v = p0[(int64_t)i * H_SZ] + p1[(int64_t)i * H_SZ];
    s += v;
    s2 += v * v;
  }
  __shared__ float ss[4][64];
  __shared__ float sq[4][64];
  ss[ty][tx] = s;
  sq[ty][tx] = s2;
  __syncthreads();
  if (ty == 0) {
    float a = ss[0][tx] + ss[1][tx] + ss[2][tx] + ss[3][tx];
    float b = sq[0][tx] + sq[1][tx] + sq[2][tx] + sq[3][tx];
    const float mean = a * (1.0f / B_SZ);
    const float var = b * (1.0f / B_SZ) - mean * mean;
    const float rs = rsqrtf(var + 1e-4f);
    const float sc = gamma[t * H_SZ + h] * rs;
    scale[t * H_SZ + h] = sc;
    shift[t * H_SZ + h] = -mean * sc;
  }
}

// ---------- LIF recurrence per (b,h): spike count S ----------
__global__ void k_recur(const float* __restrict__ Hpart, const float* __restrict__ scale,
                        const float* __restrict__ shift, _Float16* __restrict__ S) {
  const int idx = blockIdx.x * 256 + threadIdx.x;
  const int b = idx >> 10;
  const int h = idx & 1023;
  float mem = 0.f;
  int cnt = 0;
#pragma unroll
  for (int t = 0; t < T_STEPS; ++t) {
    const int64_t i = ((int64_t)(t * B_SZ + b) << 10) + h;
    float v = Hpart[i] + Hpart[i + HPLANE];
    v = v * scale[(t << 10) + h] + shift[(t << 10) + h];
    mem = 0.95f * mem + v;
    if (mem - 1.0f > 0.0f) {
      ++cnt;
      mem -= 1.0f;
    }
  }
  S[idx] = (_Float16)cnt;
}

// ---------- GEMM2: out = S @ W2^T / 20, 2-term fp16 split (exact: S integer) ----------
__global__ void k_gemm2(const _Float16* __restrict__ S, const _Float16* __restrict__ W2h,
                        const _Float16* __restrict__ W2l, float* __restrict__ out) {
  const int wid = threadIdx.x >> 6;
  const int lane = threadIdx.x & 63;
  const int m0 = blockIdx.y * 64 + wid * 16;
  const int n0 = blockIdx.x * 16;
  const int fr = lane & 15;
  const int quad = lane >> 4;

  const _Float16* sp = S + (int64_t)(m0 + fr) * H_SZ + quad * 8;
  const _Float16* wph = W2h + (int64_t)(n0 + fr) * H_SZ + quad * 8;
  const _Float16* wpl = W2l + (int64_t)(n0 + fr) * H_SZ + quad * 8;

  f32x4 acc = {0.f, 0.f, 0.f, 0.f};
#pragma unroll 4
  for (int k = 0; k < H_SZ; k += 32) {
    half8 a = *(const half8*)(sp + k);
    half8 bh = *(const half8*)(wph + k);
    half8 bl = *(const half8*)(wpl + k);
    acc = __builtin_amdgcn_mfma_f32_16x16x32_f16(a, bh, acc, 0, 0, 0);
    acc = __builtin_amdgcn_mfma_f32_16x16x32_f16(a, bl, acc, 0, 0, 0);
  }
  const int col = n0 + fr;
  if (col < C_SZ) {
#pragma unroll
    for (int r = 0; r < 4; ++r) {
      const int row = m0 + quad * 4 + r;
      out[row * C_SZ + col] = acc[r] * (1.0f / T_STEPS);
    }
  }
}

extern "C" void kernel_launch(void* const* d_in, const int* in_sizes, int n_in,
                              void* d_out, int out_size, void* d_ws, size_t ws_size,
                              hipStream_t stream) {
  const float* z = (const float*)d_in[0];      // [20,512,4096]
  const float* W1 = (const float*)d_in[1];     // [1024,4096]
  const float* gamma = (const float*)d_in[2];  // [20,1024]
  const float* W2 = (const float*)d_in[3];     // [100,1024]
  float* out = (float*)d_out;                  // [512,100]

  char* ws = (char*)d_ws;
  size_t off = 0;
  auto alloc = [&](size_t bytes) -> void* {
    void* p = ws + off;
    off += (bytes + 255) & ~(size_t)255;
    return p;
  };
  _Float16* Azh = (_Float16*)alloc((size_t)M_TOT * D_IN * 2);
  _Float16* Azl = (_Float16*)alloc((size_t)M_TOT * D_IN * 2);
  _Float16* Wfh = (_Float16*)alloc((size_t)H_SZ * D_IN * 2);
  _Float16* Wfl = (_Float16*)alloc((size_t)H_SZ * D_IN * 2);
  float* Hpart = (float*)alloc((size_t)2 * M_TOT * H_SZ * 4);  // two K-half planes
  float* scale = (float*)alloc((size_t)T_STEPS * H_SZ * 4);
  float* shift = (float*)alloc((size_t)T_STEPS * H_SZ * 4);
  _Float16* S = (_Float16*)alloc((size_t)B_SZ * H_SZ * 2);
  _Float16* W2h = (_Float16*)alloc((size_t)112 * H_SZ * 2);
  _Float16* W2l = (_Float16*)alloc((size_t)112 * H_SZ * 2);

  // 1) z + W1 -> fragment-tiled fp16 hi/lo planes (LDS-transposed, coalesced); W2 hi/lo
  dim3 gp(16, 352);  // 16 col-chunks x (88 rt * 4 rb)
  k_prep_frag<<<gp, 256, 0, stream>>>(z, Azh, Azl, W1, Wfh, Wfl);
  k_prep_w2<<<(112 * H_SZ) / 256, 256, 0, stream>>>(W2, W2h, W2l);

  // 2) batched fc1 GEMM: split-K x2, 1-phase single-buffer (verified structure)
  k_gemm1<<<1280, 256, 0, stream>>>(Azh, Azl, Wfh, Wfl, Hpart);

  // 3) BN stats (folds the two partial planes)
  dim3 gs(H_SZ / 64, T_STEPS);  // (16, 20)
  k_stats<<<gs, 256, 0, stream>>>(Hpart, gamma, scale, shift);

  // 4) LIF recurrence -> spike counts (folds partials)
  k_recur<<<(B_SZ * H_SZ) / 256, 256, 0, stream>>>(Hpart, scale, shift, S);

  // 5) spike-count GEMM -> output
  dim3 g2(7, 8);
  k_gemm2<<<g2, 256, 0, stream>>>(S, W2h, W2l, out);
}